// Round 8
// baseline (3790.479 us; speedup 1.0000x reference)
//
#include <hip/hip_runtime.h>
#include <hip/hip_bf16.h>
#include <stdint.h>

using bf16 = __hip_bfloat16;

#define NEG_SLOPE 0.2f
// Problem constants
#define NB   8
#define NT   12
#define NN   512
#define NF   288
#define NE   8192
#define NM   96     // NT*NB
#define RR   49152  // NN*NM
#define OUT1OFF 14155776ull   // ELEMENTS in output0 (f32); byte offset = 4*this

// Scratch lives INSIDE d_out's output1 region (f32: 100.6 MB avail, 32 MB used).
// k_attn (last) fully overwrites output1. Zero d_ws usage.
#define SOFF_H    0ull          // bf16 [RR*288] = 28,311,552 B
#define SOFF_EL   28311552ull   // f32  [3*RR*3] = 1,769,472 B
#define SOFF_ER   30081024ull   // f32  [3*RR*3]
#define SOFF_OFFS 31850496ull   // int  [3*513]
#define SOFF_CURS 31858688ull   // int  [3*512]
#define SOFF_ESRC 31866880ull   // int  [3*8192]  (ends 31,965,184 < 100,663,296)

// ---- adaptive index reading (int32 or int64 input buffers) ------------------
static __device__ __forceinline__ bool idx_is64(const int* p) {
    bool z = true;
#pragma unroll
    for (int i = 1; i < 16; i += 2) z = z && (p[i] == 0);
    return z;
}
static __device__ __forceinline__ int geti(const int* p, bool m64, int e) {
    return m64 ? p[2 * e] : p[e];
}
// -----------------------------------------------------------------------------

__global__ void k_zero(int* curs) {
    int i = blockIdx.x * 256 + threadIdx.x;
    if (i < 3 * 512) curs[i] = 0;
}

__global__ void k_count(const int* dd, const int* dm, const int* ds, int* curs) {
    int i = blockIdx.x * 256 + threadIdx.x;
    if (i >= 3 * NE) return;
    int g = i >> 13, e = i & (NE - 1);
    const int* dp = g == 0 ? dd : (g == 1 ? dm : ds);
    bool m64 = idx_is64(dp);
    atomicAdd(&curs[g * NN + geti(dp, m64, e)], 1);
}

__global__ void k_scan(int* curs, int* offs) {
    __shared__ int sc[NN];
    int g = blockIdx.x, t = threadIdx.x;
    sc[t] = curs[g * NN + t];
    curs[g * NN + t] = 0;
    __syncthreads();
    for (int off = 1; off < NN; off <<= 1) {
        int v = (t >= off) ? sc[t - off] : 0;
        __syncthreads();
        sc[t] += v;
        __syncthreads();
    }
    offs[g * 513 + t + 1] = sc[t];
    if (t == 0) offs[g * 513] = 0;
}

__global__ void k_fill(const int* sd, const int* dd, const int* sm, const int* dm,
                       const int* ss, const int* ds,
                       const int* offs, int* curs, int* esrc) {
    int i = blockIdx.x * 256 + threadIdx.x;
    if (i >= 3 * NE) return;
    int g = i >> 13, e = i & (NE - 1);
    const int* sp = g == 0 ? sd : (g == 1 ? sm : ss);
    const int* dp = g == 0 ? dd : (g == 1 ? dm : ds);
    bool s64 = idx_is64(sp), d64 = idx_is64(dp);
    int d = geti(dp, d64, e);
    int pos = atomicAdd(&curs[g * NN + d], 1);
    esrc[g * NE + offs[g * 513 + d] + pos] = geti(sp, s64, e);
}

// Fused brute-force h + el + er: thread = (r, g, hh). 32 f32 column dots,
// el/er computed from the f32 accumulators.
__global__ __launch_bounds__(256) void k_h2(const float* x_in, const float* cov,
                                            const float* Wd, const float* Wm, const float* Wsp,
                                            const float* ald, const float* ard,
                                            const float* alm, const float* arm,
                                            const float* als, const float* ars,
                                            bf16* hws, float* el, float* er) {
    int i = blockIdx.x * 256 + threadIdx.x;
    if (i >= RR * 9) return;
    int r = i / 9, q = i - r * 9;
    int g = q / 3, hh = q - g * 3;
    const float* W = g == 0 ? Wd : (g == 1 ? Wm : Wsp);
    const float* al = g == 0 ? ald : (g == 1 ? alm : als);
    const float* ar = g == 0 ? ard : (g == 1 ? arm : ars);
    int n = r / 96, m = r - n * 96;
    int bb = m & 7, tt = m >> 3;
    size_t xb = ((size_t)((bb * 12 + tt) * 512 + n)) * NF;
    float acc[32];
#pragma unroll
    for (int c = 0; c < 32; c++) acc[c] = 0.f;
    for (int f = 0; f < NF; f++) {
        float xv = x_in[xb + f] + cov[xb + f];
        const float* wrow = W + (size_t)f * 96 + hh * 32;
#pragma unroll
        for (int c = 0; c < 32; c++) acc[c] = fmaf(xv, wrow[c], acc[c]);
    }
    float sl = 0.f, sr = 0.f;
    size_t hb = (size_t)r * NF + (size_t)g * 96 + hh * 32;
    for (int c = 0; c < 32; c++) {
        hws[hb + c] = __float2bfloat16(acc[c]);
        sl = fmaf(acc[c], al[hh * 32 + c], sl);
        sr = fmaf(acc[c], ar[hh * 32 + c], sr);
    }
    el[(size_t)(g * RR + r) * 3 + hh] = sl;
    er[(size_t)(g * RR + r) * 3 + hh] = sr;
}

// Aggregation: block = (dst n, graph g); 192 threads = (m-parity, col j).
// Writes FLOAT32 output.
__global__ __launch_bounds__(192) void k_agg_simple(const float* x_in,
                                                    const bf16* hws,
                                                    const float* el,
                                                    const float* er,
                                                    const int* offs,
                                                    const int* esrc,
                                                    const float* bd, const float* bm, const float* bs,
                                                    float* out) {
    int t = threadIdx.x;
    int mloc = t / 96;
    int j = t - mloc * 96;
    int n = blockIdx.x, g = blockIdx.y;
    const float* bias = g == 0 ? bd : (g == 1 ? bm : bs);
    int hh = j >> 5, dd = j & 31;
    int e0 = offs[g * 513 + n], e1 = offs[g * 513 + n + 1];

    for (int mb = 0; mb < 96; mb += 2) {
        int m = mb + mloc;
        float ern = er[((size_t)g * RR + (size_t)n * 96 + m) * 3 + hh];
        float mx = -1e30f;
        for (int e = e0; e < e1; ++e) {
            int s = esrc[g * NE + e];
            float v = el[((size_t)g * RR + (size_t)s * 96 + m) * 3 + hh] + ern;
            v = v > 0.f ? v : NEG_SLOPE * v;
            mx = fmaxf(mx, v);
        }
        float sum = 0.f, acc = 0.f;
        for (int e = e0; e < e1; ++e) {
            int s = esrc[g * NE + e];
            float v = el[((size_t)g * RR + (size_t)s * 96 + m) * 3 + hh] + ern;
            v = v > 0.f ? v : NEG_SLOPE * v;
            float ex = expf(v - mx);
            sum += ex;
            float hv = __bfloat162float(hws[((size_t)s * 96 + m) * NF + (size_t)g * 96 + j]);
            acc = fmaf(ex, hv, acc);
        }
        float scale = sum > 0.f ? 1.f / sum : 0.f;   // deg==0 -> bias + residual only
        size_t oidx = ((size_t)m * NN + n) * NF + (size_t)hh * 96 + (size_t)g * 32 + dd;
        out[oidx] = acc * scale + bias[j] + x_in[oidx];
    }
}

// Diagnostics sentinel (adds to out[0] ONLY on failure). Decode:
// 3000=NaN el/er, 2000=|el/er|>100, 1200=esrc range, 1000=CSR total, 500=deg>128.
__global__ void k_diag(const float* el, const float* er, const int* offs,
                       const int* esrc, float* out) {
    __shared__ int flag;
    if (threadIdx.x == 0) flag = 0;
    __syncthreads();
    for (int i = threadIdx.x; i < 3 * RR * 3; i += 256) {
        float a = el[i], b = er[i];
        if (!isfinite(a) || !isfinite(b)) atomicOr(&flag, 1);
        if (fabsf(a) > 100.f || fabsf(b) > 100.f) atomicOr(&flag, 2);
    }
    for (int i = threadIdx.x; i < 3 * NE; i += 256) {
        int s = esrc[i];
        if (s < 0 || s >= NN) atomicOr(&flag, 4);
    }
    for (int g = 0; g < 3; g++) {
        if (threadIdx.x == 0 && offs[g * 513 + 512] != NE) atomicOr(&flag, 8);
        for (int n = threadIdx.x; n < NN; n += 256) {
            int d = offs[g * 513 + n + 1] - offs[g * 513 + n];
            if (d < 0 || d > 128) atomicOr(&flag, 16);
        }
    }
    __syncthreads();
    if (threadIdx.x == 0) {
        float S = 0.f;
        if (flag & 1) S = 3000.f;
        else if (flag & 2) S = 2000.f;
        else if (flag & 4) S = 1200.f;
        else if (flag & 8) S = 1000.f;
        else if (flag & 16) S = 500.f;
        if (S > 0.f) out[0] += S;
    }
}

// Output 1 (f32): softmax(cov0 @ cov0^T) rows, each written 12x. Runs LAST
// (overwrites the scratch region completely).
__global__ __launch_bounds__(256) void k_attn(const float* cov, float* out) {
    __shared__ float rowf[NF];
    __shared__ float red[16];
    int t = threadIdx.x;
    int n = blockIdx.x, b = blockIdx.y;
    size_t rb = ((size_t)(b * 12) * NN + n) * NF;
    if (t < 36) {
        float4 u0 = *reinterpret_cast<const float4*>(cov + rb + t * 8);
        float4 u1 = *reinterpret_cast<const float4*>(cov + rb + t * 8 + 4);
        rowf[t * 8 + 0] = u0.x; rowf[t * 8 + 1] = u0.y;
        rowf[t * 8 + 2] = u0.z; rowf[t * 8 + 3] = u0.w;
        rowf[t * 8 + 4] = u1.x; rowf[t * 8 + 5] = u1.y;
        rowf[t * 8 + 6] = u1.z; rowf[t * 8 + 7] = u1.w;
    }
    __syncthreads();
    float d0 = 0.f, d1 = 0.f;
    size_t cb0 = ((size_t)(b * 12) * NN + t) * NF;
    size_t cb1 = ((size_t)(b * 12) * NN + t + 256) * NF;
    for (int f0 = 0; f0 < NF; f0 += 4) {
        float4 u0 = *reinterpret_cast<const float4*>(cov + cb0 + f0);
        float4 u1 = *reinterpret_cast<const float4*>(cov + cb1 + f0);
        d0 = fmaf(rowf[f0 + 0], u0.x, d0);
        d0 = fmaf(rowf[f0 + 1], u0.y, d0);
        d0 = fmaf(rowf[f0 + 2], u0.z, d0);
        d0 = fmaf(rowf[f0 + 3], u0.w, d0);
        d1 = fmaf(rowf[f0 + 0], u1.x, d1);
        d1 = fmaf(rowf[f0 + 1], u1.y, d1);
        d1 = fmaf(rowf[f0 + 2], u1.z, d1);
        d1 = fmaf(rowf[f0 + 3], u1.w, d1);
    }
    float mx = fmaxf(d0, d1);
#pragma unroll
    for (int off = 32; off >= 1; off >>= 1) mx = fmaxf(mx, __shfl_xor(mx, off));
    if ((t & 63) == 0) red[t >> 6] = mx;
    __syncthreads();
    mx = fmaxf(fmaxf(red[0], red[1]), fmaxf(red[2], red[3]));
    float ex0 = expf(d0 - mx), ex1 = expf(d1 - mx);
    float sm = ex0 + ex1;
#pragma unroll
    for (int off = 32; off >= 1; off >>= 1) sm += __shfl_xor(sm, off);
    if ((t & 63) == 0) red[8 + (t >> 6)] = sm;
    __syncthreads();
    sm = red[8] + red[9] + red[10] + red[11];
    float inv = 1.0f / sm;
    float w0 = ex0 * inv, w1 = ex1 * inv;
#pragma unroll
    for (int j = 0; j < 12; j++) {
        size_t o = OUT1OFF + ((size_t)(b + 8 * j) * NN + n) * NN;
        out[o + t] = w0;
        out[o + 256 + t] = w1;
    }
}

extern "C" void kernel_launch(void* const* d_in, const int* in_sizes, int n_in,
                              void* d_out, int out_size, void* d_ws, size_t ws_size,
                              hipStream_t stream) {
    const float* x_in = (const float*)d_in[0];
    const float* cov = (const float*)d_in[1];
    const int* sd = (const int*)d_in[2];
    const int* dd = (const int*)d_in[3];
    const float* Wd = (const float*)d_in[4];
    const float* ald = (const float*)d_in[5];
    const float* ard = (const float*)d_in[6];
    const float* bd = (const float*)d_in[7];
    const int* sm = (const int*)d_in[8];
    const int* dm = (const int*)d_in[9];
    const float* Wm = (const float*)d_in[10];
    const float* alm = (const float*)d_in[11];
    const float* arm = (const float*)d_in[12];
    const float* bm = (const float*)d_in[13];
    const int* ss = (const int*)d_in[14];
    const int* ds = (const int*)d_in[15];
    const float* Wsp = (const float*)d_in[16];
    const float* als = (const float*)d_in[17];
    const float* ars = (const float*)d_in[18];
    const float* bs = (const float*)d_in[19];
    float* out = (float*)d_out;

    // Scratch inside the f32 output1 region (overwritten by k_attn at the end).
    char* scratch = reinterpret_cast<char*>(d_out) + 4ull * OUT1OFF;
    bf16* hws = (bf16*)(scratch + SOFF_H);
    float* el = (float*)(scratch + SOFF_EL);
    float* er = (float*)(scratch + SOFF_ER);
    int* offs = (int*)(scratch + SOFF_OFFS);
    int* curs = (int*)(scratch + SOFF_CURS);
    int* esrc = (int*)(scratch + SOFF_ESRC);

    hipLaunchKernelGGL(k_zero, dim3(6), dim3(256), 0, stream, curs);
    hipLaunchKernelGGL(k_count, dim3(96), dim3(256), 0, stream, dd, dm, ds, curs);
    hipLaunchKernelGGL(k_scan, dim3(3), dim3(512), 0, stream, curs, offs);
    hipLaunchKernelGGL(k_fill, dim3(96), dim3(256), 0, stream, sd, dd, sm, dm, ss, ds, offs, curs, esrc);
    hipLaunchKernelGGL(k_h2, dim3((RR * 9 + 255) / 256), dim3(256), 0, stream,
                       x_in, cov, Wd, Wm, Wsp, ald, ard, alm, arm, als, ars, hws, el, er);
    hipLaunchKernelGGL(k_agg_simple, dim3(512, 3), dim3(192), 0, stream,
                       x_in, hws, el, er, offs, esrc, bd, bm, bs, out);
    hipLaunchKernelGGL(k_diag, dim3(1), dim3(256), 0, stream, el, er, offs, esrc, out);
    hipLaunchKernelGGL(k_attn, dim3(512, 8), dim3(256), 0, stream, cov, out);
}

// Round 9
// 1388.094 us; speedup vs baseline: 2.7307x; 2.7307x over previous
//
#include <hip/hip_runtime.h>
#include <hip/hip_bf16.h>
#include <stdint.h>

using bf16 = __hip_bfloat16;

#define NEG_SLOPE 0.2f
// Problem constants
#define NB   8
#define NT   12
#define NN   512
#define NF   288
#define NE   8192
#define NM   96     // NT*NB
#define RR   49152  // NN*NM
#define OUT1OFF 14155776ull   // ELEMENTS in output0 (f32); byte offset = 4*this

// Scratch lives INSIDE d_out's output1 region (f32: 100.6 MB avail, 32 MB used).
// k_attn (last) fully overwrites output1. Zero d_ws usage.
#define SOFF_H    0ull          // bf16 [RR*288] = 28,311,552 B
#define SOFF_EL   28311552ull   // f32  [3*RR*3] = 1,769,472 B
#define SOFF_ER   30081024ull   // f32  [3*RR*3]
#define SOFF_OFFS 31850496ull   // int  [3*513]
#define SOFF_CURS 31858688ull   // int  [3*512]
#define SOFF_ESRC 31866880ull   // int  [3*8192]  (ends 31,965,184 < 100,663,296)

// ---- adaptive index reading (int32 or int64 input buffers) ------------------
static __device__ __forceinline__ bool idx_is64(const int* p) {
    bool z = true;
#pragma unroll
    for (int i = 1; i < 16; i += 2) z = z && (p[i] == 0);
    return z;
}
static __device__ __forceinline__ int geti(const int* p, bool m64, int e) {
    return m64 ? p[2 * e] : p[e];
}
// -----------------------------------------------------------------------------

__global__ void k_zero(int* curs) {
    int i = blockIdx.x * 256 + threadIdx.x;
    if (i < 3 * 512) curs[i] = 0;
}

__global__ void k_count(const int* dd, const int* dm, const int* ds, int* curs) {
    int i = blockIdx.x * 256 + threadIdx.x;
    if (i >= 3 * NE) return;
    int g = i >> 13, e = i & (NE - 1);
    const int* dp = g == 0 ? dd : (g == 1 ? dm : ds);
    bool m64 = idx_is64(dp);
    atomicAdd(&curs[g * NN + geti(dp, m64, e)], 1);
}

__global__ void k_scan(int* curs, int* offs) {
    __shared__ int sc[NN];
    int g = blockIdx.x, t = threadIdx.x;
    sc[t] = curs[g * NN + t];
    curs[g * NN + t] = 0;
    __syncthreads();
    for (int off = 1; off < NN; off <<= 1) {
        int v = (t >= off) ? sc[t - off] : 0;
        __syncthreads();
        sc[t] += v;
        __syncthreads();
    }
    offs[g * 513 + t + 1] = sc[t];
    if (t == 0) offs[g * 513] = 0;
}

__global__ void k_fill(const int* sd, const int* dd, const int* sm, const int* dm,
                       const int* ss, const int* ds,
                       const int* offs, int* curs, int* esrc) {
    int i = blockIdx.x * 256 + threadIdx.x;
    if (i >= 3 * NE) return;
    int g = i >> 13, e = i & (NE - 1);
    const int* sp = g == 0 ? sd : (g == 1 ? sm : ss);
    const int* dp = g == 0 ? dd : (g == 1 ? dm : ds);
    bool s64 = idx_is64(sp), d64 = idx_is64(dp);
    int d = geti(dp, d64, e);
    int pos = atomicAdd(&curs[g * NN + d], 1);
    esrc[g * NE + offs[g * 513 + d] + pos] = geti(sp, s64, e);
}

// Tiled GEMM: h[r, g*96+j] = sum_f xc[r,f] * W_g[f,j]; block = 64 rows x 96 cols.
#define KC 32
__global__ __launch_bounds__(256) void k_gemm(const float* __restrict__ x_in,
                                              const float* __restrict__ cov,
                                              const float* __restrict__ Wd,
                                              const float* __restrict__ Wm,
                                              const float* __restrict__ Wsp,
                                              bf16* __restrict__ hws) {
    __shared__ float xs[64][36];
    __shared__ float wls[KC][96];
    int t = threadIdx.x;
    int r0 = blockIdx.x * 64;
    int g = blockIdx.y;
    const float* W = g == 0 ? Wd : (g == 1 ? Wm : Wsp);

    // x staging: thread loads 8 k's of one row
    int xi = t >> 2;
    int xk = (t & 3) * 8;
    int r = r0 + xi;
    int n = r / 96, m = r % 96;
    int bb = m & 7, tt = m >> 3;
    size_t xbase = ((size_t)((bb * 12 + tt) * 512 + n)) * NF;
    // W staging: thread loads 12 cols of one k-row
    int wf = t >> 3;
    int wj = (t & 7) * 12;

    int tr = (t >> 4) * 4;
    int tc = (t & 15) * 6;
    float acc[4][6];
#pragma unroll
    for (int i = 0; i < 4; i++)
#pragma unroll
        for (int j = 0; j < 6; j++) acc[i][j] = 0.f;

    for (int k0 = 0; k0 < NF; k0 += KC) {
        float4 a0 = *reinterpret_cast<const float4*>(x_in + xbase + k0 + xk);
        float4 a1 = *reinterpret_cast<const float4*>(x_in + xbase + k0 + xk + 4);
        float4 c0 = *reinterpret_cast<const float4*>(cov + xbase + k0 + xk);
        float4 c1 = *reinterpret_cast<const float4*>(cov + xbase + k0 + xk + 4);
        xs[xi][xk + 0] = a0.x + c0.x;
        xs[xi][xk + 1] = a0.y + c0.y;
        xs[xi][xk + 2] = a0.z + c0.z;
        xs[xi][xk + 3] = a0.w + c0.w;
        xs[xi][xk + 4] = a1.x + c1.x;
        xs[xi][xk + 5] = a1.y + c1.y;
        xs[xi][xk + 6] = a1.z + c1.z;
        xs[xi][xk + 7] = a1.w + c1.w;

        const float4* pw = reinterpret_cast<const float4*>(W + (size_t)(k0 + wf) * 96 + wj);
        float4 w0 = pw[0], w1 = pw[1], w2 = pw[2];
        wls[wf][wj + 0] = w0.x;  wls[wf][wj + 1] = w0.y;
        wls[wf][wj + 2] = w0.z;  wls[wf][wj + 3] = w0.w;
        wls[wf][wj + 4] = w1.x;  wls[wf][wj + 5] = w1.y;
        wls[wf][wj + 6] = w1.z;  wls[wf][wj + 7] = w1.w;
        wls[wf][wj + 8] = w2.x;  wls[wf][wj + 9] = w2.y;
        wls[wf][wj + 10] = w2.z; wls[wf][wj + 11] = w2.w;
        __syncthreads();
#pragma unroll
        for (int kk = 0; kk < KC; kk++) {
            float a0v = xs[tr + 0][kk], a1v = xs[tr + 1][kk];
            float a2v = xs[tr + 2][kk], a3v = xs[tr + 3][kk];
            const float2* w2p = reinterpret_cast<const float2*>(&wls[kk][tc]);
            float2 b01 = w2p[0], b23 = w2p[1], b45 = w2p[2];
            float b[6] = {b01.x, b01.y, b23.x, b23.y, b45.x, b45.y};
#pragma unroll
            for (int j = 0; j < 6; j++) {
                acc[0][j] = fmaf(a0v, b[j], acc[0][j]);
                acc[1][j] = fmaf(a1v, b[j], acc[1][j]);
                acc[2][j] = fmaf(a2v, b[j], acc[2][j]);
                acc[3][j] = fmaf(a3v, b[j], acc[3][j]);
            }
        }
        __syncthreads();
    }
    // Scalar bf16 epilogue (proven safe).
#pragma unroll
    for (int i = 0; i < 4; i++) {
        int row = r0 + tr + i;
        size_t hb = (size_t)row * NF + (size_t)g * 96 + tc;
#pragma unroll
        for (int j = 0; j < 6; j++) {
            hws[hb + j] = __float2bfloat16(acc[i][j]);
        }
    }
}

// el/er from bf16 h: thread = (r, g, hh); vectorized uint4 reads of h.
__global__ void k_e(const bf16* __restrict__ hws,
                    const float* ald, const float* ard, const float* alm, const float* arm,
                    const float* als, const float* ars,
                    float* __restrict__ el, float* __restrict__ er) {
    int i = blockIdx.x * 256 + threadIdx.x;
    if (i >= RR * 9) return;
    int r = i / 9, q = i % 9;
    int g = q / 3, hh = q % 3;
    const float* al = g == 0 ? ald : (g == 1 ? alm : als);
    const float* ar = g == 0 ? ard : (g == 1 ? arm : ars);
    size_t hb = (size_t)r * NF + (size_t)g * 96 + hh * 32;
    float sl = 0.f, sr = 0.f;
#pragma unroll
    for (int v = 0; v < 4; v++) {
        uint4 uh = *reinterpret_cast<const uint4*>(hws + hb + v * 8);
        float4 pa0 = *reinterpret_cast<const float4*>(al + hh * 32 + v * 8);
        float4 pa1 = *reinterpret_cast<const float4*>(al + hh * 32 + v * 8 + 4);
        float4 pb0 = *reinterpret_cast<const float4*>(ar + hh * 32 + v * 8);
        float4 pb1 = *reinterpret_cast<const float4*>(ar + hh * 32 + v * 8 + 4);
        const unsigned short* ph = reinterpret_cast<const unsigned short*>(&uh);
        float av[8] = {pa0.x, pa0.y, pa0.z, pa0.w, pa1.x, pa1.y, pa1.z, pa1.w};
        float bv[8] = {pb0.x, pb0.y, pb0.z, pb0.w, pb1.x, pb1.y, pb1.z, pb1.w};
#pragma unroll
        for (int j = 0; j < 8; j++) {
            float hv = __uint_as_float(((unsigned)ph[j]) << 16);
            sl = fmaf(hv, av[j], sl);
            sr = fmaf(hv, bv[j], sr);
        }
    }
    el[(size_t)(g * RR + r) * 3 + hh] = sl;
    er[(size_t)(g * RR + r) * 3 + hh] = sr;
}

// Aggregation: block = (dst n, graph g); 192 threads = (m-parity, col j).
__global__ __launch_bounds__(192) void k_agg_simple(const float* x_in,
                                                    const bf16* hws,
                                                    const float* el,
                                                    const float* er,
                                                    const int* offs,
                                                    const int* esrc,
                                                    const float* bd, const float* bm, const float* bs,
                                                    float* out) {
    int t = threadIdx.x;
    int mloc = t / 96;
    int j = t - mloc * 96;
    int n = blockIdx.x, g = blockIdx.y;
    const float* bias = g == 0 ? bd : (g == 1 ? bm : bs);
    int hh = j >> 5, dd = j & 31;
    int e0 = offs[g * 513 + n], e1 = offs[g * 513 + n + 1];

    for (int mb = 0; mb < 96; mb += 2) {
        int m = mb + mloc;
        float ern = er[((size_t)g * RR + (size_t)n * 96 + m) * 3 + hh];
        float mx = -1e30f;
        for (int e = e0; e < e1; ++e) {
            int s = esrc[g * NE + e];
            float v = el[((size_t)g * RR + (size_t)s * 96 + m) * 3 + hh] + ern;
            v = v > 0.f ? v : NEG_SLOPE * v;
            mx = fmaxf(mx, v);
        }
        float sum = 0.f, acc = 0.f;
        for (int e = e0; e < e1; ++e) {
            int s = esrc[g * NE + e];
            float v = el[((size_t)g * RR + (size_t)s * 96 + m) * 3 + hh] + ern;
            v = v > 0.f ? v : NEG_SLOPE * v;
            float ex = expf(v - mx);
            sum += ex;
            float hv = __bfloat162float(hws[((size_t)s * 96 + m) * NF + (size_t)g * 96 + j]);
            acc = fmaf(ex, hv, acc);
        }
        float scale = sum > 0.f ? 1.f / sum : 0.f;   // deg==0 -> bias + residual only
        size_t oidx = ((size_t)m * NN + n) * NF + (size_t)hh * 96 + (size_t)g * 32 + dd;
        out[oidx] = acc * scale + bias[j] + x_in[oidx];
    }
}

// Output 1 (f32): softmax(cov0 @ cov0^T) rows, each written 12x. Runs LAST
// (overwrites the scratch region completely).
__global__ __launch_bounds__(256) void k_attn(const float* cov, float* out) {
    __shared__ float rowf[NF];
    __shared__ float red[16];
    int t = threadIdx.x;
    int n = blockIdx.x, b = blockIdx.y;
    size_t rb = ((size_t)(b * 12) * NN + n) * NF;
    if (t < 36) {
        float4 u0 = *reinterpret_cast<const float4*>(cov + rb + t * 8);
        float4 u1 = *reinterpret_cast<const float4*>(cov + rb + t * 8 + 4);
        rowf[t * 8 + 0] = u0.x; rowf[t * 8 + 1] = u0.y;
        rowf[t * 8 + 2] = u0.z; rowf[t * 8 + 3] = u0.w;
        rowf[t * 8 + 4] = u1.x; rowf[t * 8 + 5] = u1.y;
        rowf[t * 8 + 6] = u1.z; rowf[t * 8 + 7] = u1.w;
    }
    __syncthreads();
    float d0 = 0.f, d1 = 0.f;
    size_t cb0 = ((size_t)(b * 12) * NN + t) * NF;
    size_t cb1 = ((size_t)(b * 12) * NN + t + 256) * NF;
    for (int f0 = 0; f0 < NF; f0 += 4) {
        float4 u0 = *reinterpret_cast<const float4*>(cov + cb0 + f0);
        float4 u1 = *reinterpret_cast<const float4*>(cov + cb1 + f0);
        d0 = fmaf(rowf[f0 + 0], u0.x, d0);
        d0 = fmaf(rowf[f0 + 1], u0.y, d0);
        d0 = fmaf(rowf[f0 + 2], u0.z, d0);
        d0 = fmaf(rowf[f0 + 3], u0.w, d0);
        d1 = fmaf(rowf[f0 + 0], u1.x, d1);
        d1 = fmaf(rowf[f0 + 1], u1.y, d1);
        d1 = fmaf(rowf[f0 + 2], u1.z, d1);
        d1 = fmaf(rowf[f0 + 3], u1.w, d1);
    }
    float mx = fmaxf(d0, d1);
#pragma unroll
    for (int off = 32; off >= 1; off >>= 1) mx = fmaxf(mx, __shfl_xor(mx, off));
    if ((t & 63) == 0) red[t >> 6] = mx;
    __syncthreads();
    mx = fmaxf(fmaxf(red[0], red[1]), fmaxf(red[2], red[3]));
    float ex0 = expf(d0 - mx), ex1 = expf(d1 - mx);
    float sm = ex0 + ex1;
#pragma unroll
    for (int off = 32; off >= 1; off >>= 1) sm += __shfl_xor(sm, off);
    if ((t & 63) == 0) red[8 + (t >> 6)] = sm;
    __syncthreads();
    sm = red[8] + red[9] + red[10] + red[11];
    float inv = 1.0f / sm;
    float w0 = ex0 * inv, w1 = ex1 * inv;
#pragma unroll
    for (int j = 0; j < 12; j++) {
        size_t o = OUT1OFF + ((size_t)(b + 8 * j) * NN + n) * NN;
        out[o + t] = w0;
        out[o + 256 + t] = w1;
    }
}

extern "C" void kernel_launch(void* const* d_in, const int* in_sizes, int n_in,
                              void* d_out, int out_size, void* d_ws, size_t ws_size,
                              hipStream_t stream) {
    const float* x_in = (const float*)d_in[0];
    const float* cov = (const float*)d_in[1];
    const int* sd = (const int*)d_in[2];
    const int* dd = (const int*)d_in[3];
    const float* Wd = (const float*)d_in[4];
    const float* ald = (const float*)d_in[5];
    const float* ard = (const float*)d_in[6];
    const float* bd = (const float*)d_in[7];
    const int* sm = (const int*)d_in[8];
    const int* dm = (const int*)d_in[9];
    const float* Wm = (const float*)d_in[10];
    const float* alm = (const float*)d_in[11];
    const float* arm = (const float*)d_in[12];
    const float* bm = (const float*)d_in[13];
    const int* ss = (const int*)d_in[14];
    const int* ds = (const int*)d_in[15];
    const float* Wsp = (const float*)d_in[16];
    const float* als = (const float*)d_in[17];
    const float* ars = (const float*)d_in[18];
    const float* bs = (const float*)d_in[19];
    float* out = (float*)d_out;

    // Scratch inside the f32 output1 region (overwritten by k_attn at the end).
    char* scratch = reinterpret_cast<char*>(d_out) + 4ull * OUT1OFF;
    bf16* hws = (bf16*)(scratch + SOFF_H);
    float* el = (float*)(scratch + SOFF_EL);
    float* er = (float*)(scratch + SOFF_ER);
    int* offs = (int*)(scratch + SOFF_OFFS);
    int* curs = (int*)(scratch + SOFF_CURS);
    int* esrc = (int*)(scratch + SOFF_ESRC);

    hipLaunchKernelGGL(k_zero, dim3(6), dim3(256), 0, stream, curs);
    hipLaunchKernelGGL(k_count, dim3(96), dim3(256), 0, stream, dd, dm, ds, curs);
    hipLaunchKernelGGL(k_scan, dim3(3), dim3(512), 0, stream, curs, offs);
    hipLaunchKernelGGL(k_fill, dim3(96), dim3(256), 0, stream, sd, dd, sm, dm, ss, ds, offs, curs, esrc);
    hipLaunchKernelGGL(k_gemm, dim3(768, 3), dim3(256), 0, stream, x_in, cov, Wd, Wm, Wsp, hws);
    hipLaunchKernelGGL(k_e, dim3(1728), dim3(256), 0, stream,
                       hws, ald, ard, alm, arm, als, ars, el, er);
    hipLaunchKernelGGL(k_agg_simple, dim3(512, 3), dim3(192), 0, stream,
                       x_in, hws, el, er, offs, esrc, bd, bm, bs, out);
    hipLaunchKernelGGL(k_attn, dim3(512, 8), dim3(256), 0, stream, cov, out);
}